// Round 7
// baseline (237.800 us; speedup 1.0000x reference)
//
#include <hip/hip_runtime.h>

// EMA y_t = 0.1*x_t + 0.9*y_{t-1} along T of x[B=64][T=8192][F=64], fp32.
// R11: sustained in-flight attack. R4-R10 post-mortem: time (79-91us) is
// invariant to structure AND traffic (197-234MB) -> latency-bound, not BW.
// Effective in-flight per CU ~3.7KB (2.5TB/s x 375ns / 256CU): prior
// kernels either hold ~1 load continuously (compiler-collapsed reg staging)
// or hold 32KB briefly (R10 DMA burst, then a long 0-outstanding compute/
// teardown window at 2.8 waves/CU avg). Fill/copy kernels win with many
// waves each continuously holding a few ops. Fix: max occupancy x constant
// per-wave depth, all memory ops in inline asm (SIInsertWaitcnts ignores
// asm ops -> no hidden vmcnt(0)), AITER-style counted vmcnt, never 0 in
// steady state:
//   - 1 float/lane, wave = chunk of L=64 stored + H=64 windup rows;
//   - register ring rA..rD of 8 rows (256B/instr coalesced), depth-4:
//     >=24 loads (6KB) outstanding per wave at all times;
//   - stores get 3 iterations of ack slack (never awaited to 0);
//   - 8192 waves = 1024 blocks x 512thr, launch_bounds(512,8) -> <=64
//     VGPR -> 32 waves/CU -> ~192KB sustained in flight per CU.
// vmcnt bookkeeping is derived per-line below (in-order decrement, loads
// and stores share the counter). XCD-swizzle keeps windup re-reads local.
// Numerics unchanged: H=64 (0.9^64~1.2e-3), chunk 0 exact (y_0=x_0).

constexpr int Tn = 8192;
constexpr int Fn = 64;      // features = lanes
constexpr int Ln = 64;      // stored rows per wave
constexpr int Hn = 64;      // windup rows
constexpr int NC = Tn / Ln; // 128 chunks per batch row
constexpr float ALPHA = 0.1f;
constexpr float OMA   = 0.9f;

// wait until <= N vector-memory ops outstanding; fence so FMAs on asm-load
// results can't hoist above the wait (rule #18).
#define WAITV(N) do { asm volatile("s_waitcnt vmcnt(" #N ")" ::: "memory"); \
                      __builtin_amdgcn_sched_barrier(0); } while (0)

#define LD1(dst, p, BOFF) \
  asm volatile("global_load_dword %0, %1, off offset:" #BOFF \
               : "=v"(dst) : "v"(p) : "memory")

#define ST1(p, val, BOFF) \
  asm volatile("global_store_dword %0, %1, off offset:" #BOFF \
               :: "v"(p), "v"(val) : "memory")

// one batch = 8 consecutive rows, per-lane stride 256B -> offsets 0..1792
#define LD8(R, p) do { \
  LD1(R[0], (p), 0);    LD1(R[1], (p), 256);  LD1(R[2], (p), 512);  \
  LD1(R[3], (p), 768);  LD1(R[4], (p), 1024); LD1(R[5], (p), 1280); \
  LD1(R[6], (p), 1536); LD1(R[7], (p), 1792); } while (0)

#define C8(R) do { \
  s = fmaf(OMA, s, ALPHA * R[0]); s = fmaf(OMA, s, ALPHA * R[1]); \
  s = fmaf(OMA, s, ALPHA * R[2]); s = fmaf(OMA, s, ALPHA * R[3]); \
  s = fmaf(OMA, s, ALPHA * R[4]); s = fmaf(OMA, s, ALPHA * R[5]); \
  s = fmaf(OMA, s, ALPHA * R[6]); s = fmaf(OMA, s, ALPHA * R[7]); } while (0)

#define C8S(R, q) do { \
  s = fmaf(OMA, s, ALPHA * R[0]); ST1((q), s, 0);    \
  s = fmaf(OMA, s, ALPHA * R[1]); ST1((q), s, 256);  \
  s = fmaf(OMA, s, ALPHA * R[2]); ST1((q), s, 512);  \
  s = fmaf(OMA, s, ALPHA * R[3]); ST1((q), s, 768);  \
  s = fmaf(OMA, s, ALPHA * R[4]); ST1((q), s, 1024); \
  s = fmaf(OMA, s, ALPHA * R[5]); ST1((q), s, 1280); \
  s = fmaf(OMA, s, ALPHA * R[6]); ST1((q), s, 1536); \
  s = fmaf(OMA, s, ALPHA * R[7]); ST1((q), s, 1792); } while (0)

// chunk-0 first batch: y_0 = x_0 exact, then the chain
#define C8S0(R, q) do { \
  s = R[0];                       ST1((q), s, 0);    \
  s = fmaf(OMA, s, ALPHA * R[1]); ST1((q), s, 256);  \
  s = fmaf(OMA, s, ALPHA * R[2]); ST1((q), s, 512);  \
  s = fmaf(OMA, s, ALPHA * R[3]); ST1((q), s, 768);  \
  s = fmaf(OMA, s, ALPHA * R[4]); ST1((q), s, 1024); \
  s = fmaf(OMA, s, ALPHA * R[5]); ST1((q), s, 1280); \
  s = fmaf(OMA, s, ALPHA * R[6]); ST1((q), s, 1536); \
  s = fmaf(OMA, s, ALPHA * R[7]); ST1((q), s, 1792); } while (0)

__global__ __launch_bounds__(512, 8) void ema_kernel(const float* __restrict__ x,
                                                     float* __restrict__ y) {
    const int lane = threadIdx.x & 63;
    // XCD swizzle (bijective, 1024 = 8*128): XCD k owns a contiguous range
    // of (b,c) streams -> windup re-reads are L2/L3-local.
    const int swz = ((blockIdx.x & 7) << 7) | (blockIdx.x >> 3); // 0..1023
    const int G   = (swz << 3) | (threadIdx.x >> 6);             // stream 0..8191
    const int b   = G >> 7;          // 0..63
    const int c   = G & (NC - 1);    // 0..127

    const size_t bb = (size_t)b * (Tn * Fn);
    const int t0 = c * Ln;
    const int tstart = (c == 0) ? 0 : t0 - Hn;

    const float* px = x + bb + (size_t)tstart * Fn + lane;
    float*       py = y + bb + (size_t)t0 * Fn + lane;

    float rA[8], rB[8], rC[8], rD[8];
    float s = 0.0f;

    if (c != 0) {
        // 16 batches: b0..b7 windup, b8..b15 stored. Depth-4 prologue.
        LD8(rA, px + 0 * 512);
        LD8(rB, px + 1 * 512);
        LD8(rC, px + 2 * 512);
        LD8(rD, px + 3 * 512);
        // windup k=0..7: newer-than-b(k) = 3 batches = 24 ops
        WAITV(24); C8(rA); LD8(rA, px + 4 * 512);
        WAITV(24); C8(rB); LD8(rB, px + 5 * 512);
        WAITV(24); C8(rC); LD8(rC, px + 6 * 512);
        WAITV(24); C8(rD); LD8(rD, px + 7 * 512);
        WAITV(24); C8(rA); LD8(rA, px + 8 * 512);
        WAITV(24); C8(rB); LD8(rB, px + 9 * 512);
        WAITV(24); C8(rC); LD8(rC, px + 10 * 512);
        WAITV(24); C8(rD); LD8(rD, px + 11 * 512);
        // stored k=8..15; newer-than-b(k) counts (loads + prior stores,
        // in-order decrement): 24,32,40,48,48,40,32,24
        WAITV(24); C8S(rA, py + 0 * 512); LD8(rA, px + 12 * 512);
        WAITV(32); C8S(rB, py + 1 * 512); LD8(rB, px + 13 * 512);
        WAITV(40); C8S(rC, py + 2 * 512); LD8(rC, px + 14 * 512);
        WAITV(48); C8S(rD, py + 3 * 512); LD8(rD, px + 15 * 512);
        WAITV(48); C8S(rA, py + 4 * 512);
        WAITV(40); C8S(rB, py + 5 * 512);
        WAITV(32); C8S(rC, py + 6 * 512);
        WAITV(24); C8S(rD, py + 7 * 512);
    } else {
        // chunk 0: 8 stored batches, exact start.
        LD8(rA, px + 0 * 512);
        LD8(rB, px + 1 * 512);
        LD8(rC, px + 2 * 512);
        LD8(rD, px + 3 * 512);
        // counts: 24,32,40,48,48,40,32,24 (same derivation)
        WAITV(24); C8S0(rA, py + 0 * 512); LD8(rA, px + 4 * 512);
        WAITV(32); C8S(rB, py + 1 * 512);  LD8(rB, px + 5 * 512);
        WAITV(40); C8S(rC, py + 2 * 512);  LD8(rC, px + 6 * 512);
        WAITV(48); C8S(rD, py + 3 * 512);  LD8(rD, px + 7 * 512);
        WAITV(48); C8S(rA, py + 4 * 512);
        WAITV(40); C8S(rB, py + 5 * 512);
        WAITV(32); C8S(rC, py + 6 * 512);
        WAITV(24); C8S(rD, py + 7 * 512);
    }
}

extern "C" void kernel_launch(void* const* d_in, const int* in_sizes, int n_in,
                              void* d_out, int out_size, void* d_ws, size_t ws_size,
                              hipStream_t stream) {
    const float* x = (const float*)d_in[0];
    float*       y = (float*)d_out;
    // 8192 wave-streams; 1024 blocks x 512 thr (8 waves); 4 blocks/CU,
    // 32 waves/CU if VGPR <= 64 (launch_bounds-pinned).
    ema_kernel<<<dim3(1024), dim3(512), 0, stream>>>(x, y);
}